// Round 17
// baseline (411.996 us; speedup 1.0000x reference)
//
#include <hip/hip_runtime.h>
#include <math.h>

#define HD 64
#define FIN 512
#define NC 40

struct __align__(8) EdgeT { int s; float v; };

typedef __attribute__((ext_vector_type(8))) short bf16x8;
typedef __attribute__((ext_vector_type(8))) unsigned short u16x8;
typedef __attribute__((ext_vector_type(4))) float f32x4;

__device__ __forceinline__ float bf2f(ushort u) {
    return __uint_as_float(((unsigned int)u) << 16);
}
__device__ __forceinline__ ushort f2bf(float f) {
    unsigned int u = __float_as_uint(f);
    unsigned int r = (u + 0x7fffu + ((u >> 16) & 1u)) >> 16;   // RNE
    return (ushort)r;
}

// ---------------- prep: packed8 init + all weight repacks (1 launch) ----------------
// packed8[c*n+i] (uint32): bits[26:32) = per-copy edge count, bits[0:26) =
// fixed-point(2^-21) weighted degree.
// Wf2 holds W' = beta*W + (1-beta)*I  (identity mapping folded into the GEMM;
// epilogue becomes a bare relu). frag layout:
// Wf[((c*4+t)*64+l)*8+j] = W[c*32+8*(l>>4)+j][t*16+(l&15)]

__global__ __launch_bounds__(256) void prep_kernel(uint* packed8, int n,
        const float* __restrict__ Win, ushort* __restrict__ Wf,
        const float* __restrict__ Wlay, ushort* __restrict__ Wf2, int L,
        const float* __restrict__ Wo, const float* __restrict__ bo,
        ushort* __restrict__ Wfo, float* __restrict__ bo_pad) {
    int i = blockIdx.x * 256 + threadIdx.x;
    if (i < 8 * n) packed8[i] = (i < n) ? (1u << 21) : 0u;  // self-loop w=1.0 in copy 0
    if (i < FIN * HD) {
        int j = i & 7, l = (i >> 3) & 63, t = (i >> 9) & 3, c = i >> 11;
        int k = c * 32 + ((l >> 4) * 8) + j;
        Wf[i] = f2bf(Win[k * HD + t * 16 + (l & 15)]);
    }
    if (i < L * HD * HD) {
        int li = i >> 12, ii = i & 4095;
        int j = ii & 7, l = (ii >> 3) & 63, t = (ii >> 9) & 3, c = (ii >> 11) & 1;
        int k = c * 32 + ((l >> 4) * 8) + j;
        int col = t * 16 + (l & 15);
        float beta = logf(0.5f / (float)(li + 1) + 1.0f);
        float v = beta * Wlay[(size_t)li * HD * HD + k * HD + col] +
                  ((k == col) ? (1.f - beta) : 0.f);
        Wf2[i] = f2bf(v);
    }
    if (i < HD * HD) {
        int j = i & 7, l = (i >> 3) & 63, t = (i >> 9) & 3, c = (i >> 11) & 1;
        int k = c * 32 + ((l >> 4) * 8) + j;
        int col = t * 16 + (l & 15);
        Wfo[i] = (col < NC) ? f2bf(Wo[k * NC + col]) : (ushort)0;
    }
    if (i < HD) bo_pad[i] = (i < NC) ? bo[i] : 0.f;
}

// ---------------- fused: proj (MFMA) interleaved with edge histogram --------------
// Block role by blockIdx%k: r==0 -> proj tile q, else hist tile. Each hist thread
// handles 4 edges (4 independent with-return atomics in flight; R16 post-mortem:
// hist is atomic-return-latency bound, not scheduling bound).

__global__ __launch_bounds__(256) void histproj_kernel(
        const int* __restrict__ dst, const float* __restrict__ w,
        uint* packed8, ushort* __restrict__ rank, int E, int n,
        const float* __restrict__ x, const ushort* __restrict__ Wf,
        const float* __restrict__ bias, ushort* __restrict__ h0,
        int npb, int k) {
    const int q = blockIdx.x / k;
    const int r = blockIdx.x - q * k;
    if (r != 0) {
        int hid = q * (k - 1) + (r - 1);
        int i0 = hid * 1024 + threadIdx.x;
#pragma unroll
        for (int p = 0; p < 4; ++p) {
            int i = i0 + p * 256;
            if (i < E) {
                int d = dst[i];
                int c = i & 7;
                uint add = (1u << 26) | (uint)(w[i] * 2097152.0f);
                uint old = atomicAdd(&packed8[(size_t)c * n + d], add);
                rank[i] = (ushort)(old >> 26);
            }
        }
        return;
    }
    const int lane = threadIdx.x & 63;
    const int wave = threadIdx.x >> 6;
    const int row = lane & 15;
    const int g = lane >> 4;
    const int base = q * 64 + wave * 16;

    f32x4 acc[4];
#pragma unroll
    for (int t = 0; t < 4; ++t) acc[t] = (f32x4){0.f, 0.f, 0.f, 0.f};

    int nodeA = base + row;
    if (nodeA >= n) nodeA = n - 1;
    const float* xr = x + (size_t)nodeA * FIN + g * 8;

    for (int c = 0; c < 16; ++c) {
        bf16x8 afr;
        float4 v0 = *(const float4*)(xr + c * 32);
        float4 v1 = *(const float4*)(xr + c * 32 + 4);
        afr[0] = (short)f2bf(v0.x); afr[1] = (short)f2bf(v0.y);
        afr[2] = (short)f2bf(v0.z); afr[3] = (short)f2bf(v0.w);
        afr[4] = (short)f2bf(v1.x); afr[5] = (short)f2bf(v1.y);
        afr[6] = (short)f2bf(v1.z); afr[7] = (short)f2bf(v1.w);
#pragma unroll
        for (int t = 0; t < 4; ++t) {
            bf16x8 bfr = *(const bf16x8*)(Wf + ((size_t)(c * 4 + t) * 64 + lane) * 8);
            acc[t] = __builtin_amdgcn_mfma_f32_16x16x32_bf16(afr, bfr, acc[t], 0, 0, 0);
        }
    }

    float bj[4];
#pragma unroll
    for (int t = 0; t < 4; ++t) bj[t] = bias[t * 16 + row];
#pragma unroll
    for (int rr = 0; rr < 4; ++rr) {
        int node = base + g * 4 + rr;
        if (node < n) {
#pragma unroll
            for (int t = 0; t < 4; ++t) {
                float v = fmaxf(acc[t][rr] + bj[t], 0.f);
                h0[(size_t)node * HD + t * 16 + row] = f2bf(v);
            }
        }
    }
}

// fused: dinv + copy-bases (8 bytes in uint2) + per-block count scan
__global__ __launch_bounds__(256) void post_kernel(const uint* __restrict__ packed8,
        float* __restrict__ dinv, uint2* __restrict__ cbase,
        int* __restrict__ row_ptr, int* __restrict__ bsums, int n) {
    __shared__ int s[256];
    int t = threadIdx.x;
    int i = blockIdx.x * 256 + t;
    int cnt = 0;
    if (i < n) {
        int c[8];
        unsigned long long fx = 0;
#pragma unroll
        for (int k = 0; k < 8; ++k) {
            uint p = packed8[(size_t)k * n + i];
            c[k] = (int)(p >> 26);
            fx += (p & 0x3FFFFFFu);
        }
        float deg = (float)((double)fx * (1.0 / 2097152.0));
        dinv[i] = rsqrtf(deg);                     // deg >= 1 (self-loop)
        int b = 0; uint lo = 0, hi = 0;
#pragma unroll
        for (int k = 0; k < 4; ++k) { lo |= ((uint)b) << (8 * k); b += c[k]; }
#pragma unroll
        for (int k = 0; k < 4; ++k) { hi |= ((uint)b) << (8 * k); b += c[4 + k]; }
        cbase[i] = make_uint2(lo, hi);
        cnt = b;
    }
    s[t] = cnt; __syncthreads();
    for (int off = 1; off < 256; off <<= 1) {
        int u = (t >= off) ? s[t - off] : 0;
        __syncthreads();
        s[t] += u;
        __syncthreads();
    }
    if (i < n) row_ptr[i] = s[t] - cnt;
    if (t == 255) bsums[blockIdx.x] = s[255];
}

// fused top-scan + add: block b reduces bsums[0..b-1] itself (nb < 512)
__global__ __launch_bounds__(256) void scanadd_kernel(int* __restrict__ row_ptr,
        const int* __restrict__ bsums, int n, int E) {
    __shared__ int s[256];
    const int b = blockIdx.x;
    const int t = threadIdx.x;
    int v = (t < b) ? bsums[t] : 0;
    if (t + 256 < b) v += bsums[t + 256];
    s[t] = v; __syncthreads();
#pragma unroll
    for (int off = 128; off >= 1; off >>= 1) {
        if (t < off) s[t] += s[t + off];
        __syncthreads();
    }
    int prefix = s[0];
    int i = b * 256 + t;
    if (i < n) row_ptr[i] += prefix;
    if (i == 0) row_ptr[n] = E;
}

__global__ __launch_bounds__(256) void scatter_kernel(const int* __restrict__ src,
        const int* __restrict__ dst, const float* __restrict__ w,
        const float* __restrict__ dinv, const int* __restrict__ row_ptr,
        const uint2* __restrict__ cbase, const ushort* __restrict__ rank,
        EdgeT* __restrict__ ed, int E) {
    int i = blockIdx.x * 256 + threadIdx.x;
    if (i < E) {
        int s = src[i], d = dst[i];
        int c = i & 7;
        uint2 cb = cbase[d];
        int base = (int)(((c < 4) ? (cb.x >> (8 * c)) : (cb.y >> (8 * (c - 4)))) & 0xffu);
        int pos = row_ptr[d] + base + (int)rank[i];
        EdgeT e; e.s = s; e.v = dinv[s] * w[i] * dinv[d];
        ed[pos] = e;
    }
}

// ---------------- fused layer: gather(spmm) + MFMA GEMM(W') + relu ---------------
// W' = beta*W + (1-beta)*I folded in prep -> epilogue is bare relu (no sup reads).
// Gather unroll 8: 8 independent 16B loads in flight per lane.

__global__ __launch_bounds__(256) void layerm_kernel(const ushort* __restrict__ h_in,
        const ushort* __restrict__ h0, ushort* __restrict__ h_out,
        const ushort* __restrict__ Wf2, const float* __restrict__ dinv,
        const int* __restrict__ row_ptr, const EdgeT* __restrict__ ed, int n) {
    __shared__ ushort S[4][32 * 72];       // 18.4 KB
    const int lane = threadIdx.x & 63;
    const int wave = threadIdx.x >> 6;
    ushort* Sw = S[wave];
    const int wbase = (blockIdx.x * 4 + wave) * 32;
    const int gs = lane >> 3;              // node slot 0..7
    const int fl = (lane & 7) * 8;         // feature offset

#pragma unroll
    for (int p = 0; p < 4; ++p) {
        int node = wbase + p * 8 + gs;
        int nc = (node < n) ? node : n - 1;
        float di = dinv[nc];
        float sw = di * di;
        u16x8 us = *(const u16x8*)(h_in + (size_t)nc * HD + fl);
        float a[8], b[8];
#pragma unroll
        for (int j = 0; j < 8; ++j) { a[j] = sw * bf2f((ushort)us[j]); b[j] = 0.f; }

        int e = row_ptr[nc], end = row_ptr[nc + 1];
        for (; e + 8 <= end; e += 8) {
            EdgeT Ex[8];
            u16x8 ux[8];
#pragma unroll
            for (int k = 0; k < 8; ++k) Ex[k] = ed[e + k];
#pragma unroll
            for (int k = 0; k < 8; ++k)
                ux[k] = *(const u16x8*)(h_in + (size_t)Ex[k].s * HD + fl);
#pragma unroll
            for (int k = 0; k < 8; k += 2) {
#pragma unroll
                for (int j = 0; j < 8; ++j) {
                    a[j] = fmaf(Ex[k].v,     bf2f((ushort)ux[k][j]),     a[j]);
                    b[j] = fmaf(Ex[k + 1].v, bf2f((ushort)ux[k + 1][j]), b[j]);
                }
            }
        }
        for (; e + 2 <= end; e += 2) {
            EdgeT E0 = ed[e], E1 = ed[e + 1];
            u16x8 u0 = *(const u16x8*)(h_in + (size_t)E0.s * HD + fl);
            u16x8 u1 = *(const u16x8*)(h_in + (size_t)E1.s * HD + fl);
#pragma unroll
            for (int j = 0; j < 8; ++j) {
                a[j] = fmaf(E0.v, bf2f((ushort)u0[j]), a[j]);
                b[j] = fmaf(E1.v, bf2f((ushort)u1[j]), b[j]);
            }
        }
        if (e < end) {
            EdgeT E0 = ed[e];
            u16x8 u0 = *(const u16x8*)(h_in + (size_t)E0.s * HD + fl);
#pragma unroll
            for (int j = 0; j < 8; ++j) a[j] = fmaf(E0.v, bf2f((ushort)u0[j]), a[j]);
        }

        u16x8 uh = *(const u16x8*)(h0 + (size_t)nc * HD + fl);
        u16x8 r;
#pragma unroll
        for (int j = 0; j < 8; ++j)
            r[j] = f2bf(fmaf(0.9f, a[j] + b[j], 0.1f * bf2f((ushort)uh[j])));
        *(u16x8*)(Sw + (p * 8 + gs) * 72 + fl) = r;
    }

    asm volatile("s_waitcnt lgkmcnt(0)" ::: "memory");
    __builtin_amdgcn_wave_barrier();
    __builtin_amdgcn_sched_barrier(0);

    // ---- MFMA: 32 nodes x 64 cols, W' includes residual ----
    const int row = lane & 15;
    const int g = lane >> 4;
    f32x4 acc[2][4];
#pragma unroll
    for (int m = 0; m < 2; ++m)
#pragma unroll
        for (int t = 0; t < 4; ++t) acc[m][t] = (f32x4){0.f, 0.f, 0.f, 0.f};

#pragma unroll
    for (int c = 0; c < 2; ++c) {
        bf16x8 afr[2];
#pragma unroll
        for (int m = 0; m < 2; ++m)
            afr[m] = *(const bf16x8*)(Sw + (m * 16 + row) * 72 + c * 32 + g * 8);
#pragma unroll
        for (int t = 0; t < 4; ++t) {
            bf16x8 bfr = *(const bf16x8*)(Wf2 + ((size_t)(c * 4 + t) * 64 + lane) * 8);
            acc[0][t] = __builtin_amdgcn_mfma_f32_16x16x32_bf16(afr[0], bfr, acc[0][t], 0, 0, 0);
            acc[1][t] = __builtin_amdgcn_mfma_f32_16x16x32_bf16(afr[1], bfr, acc[1][t], 0, 0, 0);
        }
    }

#pragma unroll
    for (int m = 0; m < 2; ++m)
#pragma unroll
        for (int r = 0; r < 4; ++r) {
            int node = wbase + m * 16 + g * 4 + r;
            if (node < n) {
#pragma unroll
                for (int t = 0; t < 4; ++t) {
                    float v = fmaxf(acc[m][t][r], 0.f);
                    h_out[(size_t)node * HD + t * 16 + row] = f2bf(v);
                }
            }
        }
}

// ---------------- output (MFMA) + log_softmax: out = lsm(h @ W_out + b) ----------

__global__ __launch_bounds__(256) void outm_kernel(const ushort* __restrict__ A,
        const ushort* __restrict__ Wfo, const float* __restrict__ bo_pad,
        float* __restrict__ outp, int n) {
    const int lane = threadIdx.x & 63;
    const int wave = threadIdx.x >> 6;
    const int row = lane & 15;
    const int g = lane >> 4;
    const int base = blockIdx.x * 128 + wave * 32;

    f32x4 acc[2][4];
#pragma unroll
    for (int m = 0; m < 2; ++m)
#pragma unroll
        for (int t = 0; t < 4; ++t) acc[m][t] = (f32x4){0.f, 0.f, 0.f, 0.f};

#pragma unroll
    for (int c = 0; c < 2; ++c) {
        bf16x8 afr[2];
#pragma unroll
        for (int m = 0; m < 2; ++m) {
            int node = base + m * 16 + row;
            if (node >= n) node = n - 1;
            afr[m] = *(const bf16x8*)(A + (size_t)node * HD + c * 32 + g * 8);
        }
#pragma unroll
        for (int t = 0; t < 4; ++t) {
            bf16x8 bfr = *(const bf16x8*)(Wfo + ((size_t)(c * 4 + t) * 64 + lane) * 8);
            acc[0][t] = __builtin_amdgcn_mfma_f32_16x16x32_bf16(afr[0], bfr, acc[0][t], 0, 0, 0);
            acc[1][t] = __builtin_amdgcn_mfma_f32_16x16x32_bf16(afr[1], bfr, acc[1][t], 0, 0, 0);
        }
    }

    float bj[4];
#pragma unroll
    for (int t = 0; t < 4; ++t) bj[t] = bo_pad[t * 16 + row];
    const bool v2 = (row < 8);             // col = 32+row < 40
#pragma unroll
    for (int m = 0; m < 2; ++m)
#pragma unroll
        for (int r = 0; r < 4; ++r) {
            float lo[3];
            lo[0] = acc[m][0][r] + bj[0];
            lo[1] = acc[m][1][r] + bj[1];
            lo[2] = acc[m][2][r] + bj[2];
            float mx = fmaxf(lo[0], lo[1]);
            if (v2) mx = fmaxf(mx, lo[2]);
#pragma unroll
            for (int off = 1; off < 16; off <<= 1)
                mx = fmaxf(mx, __shfl_xor(mx, off, 64));
            float s = __expf(lo[0] - mx) + __expf(lo[1] - mx);
            if (v2) s += __expf(lo[2] - mx);
#pragma unroll
            for (int off = 1; off < 16; off <<= 1)
                s += __shfl_xor(s, off, 64);
            float lse = __logf(s);
            int node = base + m * 16 + g * 4 + r;
            if (node < n) {
                outp[(size_t)node * NC + row] = lo[0] - mx - lse;
                outp[(size_t)node * NC + 16 + row] = lo[1] - mx - lse;
                if (v2) outp[(size_t)node * NC + 32 + row] = lo[2] - mx - lse;
            }
        }
}

// ---------------- launch ----------------

extern "C" void kernel_launch(void* const* d_in, const int* in_sizes, int n_in,
                              void* d_out, int out_size, void* d_ws, size_t ws_size,
                              hipStream_t stream) {
    const float* x        = (const float*)d_in[0];
    const int*   eidx     = (const int*)d_in[1];
    const float* ew       = (const float*)d_in[2];
    const float* W_in     = (const float*)d_in[3];
    const float* b_in     = (const float*)d_in[4];
    const float* W_layers = (const float*)d_in[5];
    const float* W_out    = (const float*)d_in[6];
    const float* b_out    = (const float*)d_in[7];
    float* out = (float*)d_out;

    const int N = in_sizes[0] / FIN;
    const int E = in_sizes[2];
    const int L = in_sizes[5] / (HD * HD);
    const int* src = eidx;
    const int* dst = eidx + E;

    size_t off = 0;
    auto carve = [&](size_t bytes) {
        void* p = (char*)d_ws + off;
        off += (bytes + 255) & ~(size_t)255;
        return p;
    };
    uint*   packed8 = (uint*) carve((size_t)N * 8 * 4);
    float*  dinv    = (float*)carve((size_t)N * 4);
    uint2*  cbase   = (uint2*)carve((size_t)N * 8);
    int*    row_ptr = (int*)  carve((size_t)(N + 1) * 4);
    int*    bsums   = (int*)  carve(512 * 4);
    float*  bo_pad  = (float*)carve((size_t)HD * 4);
    ushort* Wf      = (ushort*)carve((size_t)FIN * HD * 2);
    ushort* Wf2     = (ushort*)carve((size_t)L * HD * HD * 2);
    ushort* Wfo     = (ushort*)carve((size_t)HD * HD * 2);
    ushort* rank    = (ushort*)carve((size_t)E * 2);
    EdgeT*  ed      = (EdgeT*)carve((size_t)E * 8);
    ushort* h0      = (ushort*)carve((size_t)N * HD * 2);
    ushort* hA      = (ushort*)carve((size_t)N * HD * 2);
    ushort* hB      = (ushort*)carve((size_t)N * HD * 2);
    (void)ws_size;

    const int NB = (N + 255) / 256;
    const int EB = (E + 255) / 256;
    const int NPB = (N + 63) / 64;            // proj blocks
    const int HB  = (E + 1023) / 1024;        // hist blocks (4 edges/thread)
    const int K   = (NPB + HB + NPB - 1) / NPB;
    const int GRID = NPB * K;

    prep_kernel<<<(8 * N + 255) / 256, 256, 0, stream>>>(packed8, N, W_in, Wf,
                                                         W_layers, Wf2, L,
                                                         W_out, b_out, Wfo, bo_pad);
    histproj_kernel<<<GRID, 256, 0, stream>>>(dst, ew, packed8, rank, E, N,
                                              x, Wf, b_in, h0, NPB, K);
    post_kernel<<<NB, 256, 0, stream>>>(packed8, dinv, cbase, row_ptr, bsums, N);
    scanadd_kernel<<<NB, 256, 0, stream>>>(row_ptr, bsums, N, E);
    scatter_kernel<<<EB, 256, 0, stream>>>(src, dst, ew, dinv, row_ptr, cbase, rank, ed, E);

    const int LB = (N + 127) / 128;           // 4 waves x 32 nodes
    const ushort* cur = h0;
    ushort* bufs[2] = { hA, hB };
    for (int i = 0; i < L; ++i) {
        ushort* nxt = bufs[i & 1];
        layerm_kernel<<<LB, 256, 0, stream>>>(cur, h0, nxt, Wf2 + (size_t)i * HD * HD,
                                              dinv, row_ptr, ed, N);
        cur = nxt;
    }

    outm_kernel<<<LB, 256, 0, stream>>>(cur, Wfo, bo_pad, out, N);
}

// Round 18
// 332.457 us; speedup vs baseline: 1.2392x; 1.2392x over previous
//
#include <hip/hip_runtime.h>
#include <math.h>

#define HD 64
#define FIN 512
#define NC 40

struct __align__(8) EdgeT { int s; float v; };

typedef __attribute__((ext_vector_type(8))) short bf16x8;
typedef __attribute__((ext_vector_type(8))) unsigned short u16x8;
typedef __attribute__((ext_vector_type(4))) float f32x4;

__device__ __forceinline__ float bf2f(ushort u) {
    return __uint_as_float(((unsigned int)u) << 16);
}
__device__ __forceinline__ ushort f2bf(float f) {
    unsigned int u = __float_as_uint(f);
    unsigned int r = (u + 0x7fffu + ((u >> 16) & 1u)) >> 16;   // RNE
    return (ushort)r;
}

// ---------------- prep: packed8 init + all weight repacks (1 launch) ----------------
// packed8[c*n+i] (uint32): bits[26:32) = per-copy edge count, bits[0:26) =
// fixed-point(2^-21) weighted degree.
// Wf2 holds W' = beta*W + (1-beta)*I (identity mapping folded; epilogue = relu).
// frag layout: Wf[((c*4+t)*64+l)*8+j] = W[c*32+8*(l>>4)+j][t*16+(l&15)]

__global__ __launch_bounds__(256) void prep_kernel(uint* packed8, int n,
        const float* __restrict__ Win, ushort* __restrict__ Wf,
        const float* __restrict__ Wlay, ushort* __restrict__ Wf2, int L,
        const float* __restrict__ Wo, const float* __restrict__ bo,
        ushort* __restrict__ Wfo, float* __restrict__ bo_pad) {
    int i = blockIdx.x * 256 + threadIdx.x;
    if (i < 8 * n) packed8[i] = (i < n) ? (1u << 21) : 0u;  // self-loop w=1.0 in copy 0
    if (i < FIN * HD) {
        int j = i & 7, l = (i >> 3) & 63, t = (i >> 9) & 3, c = i >> 11;
        int k = c * 32 + ((l >> 4) * 8) + j;
        Wf[i] = f2bf(Win[k * HD + t * 16 + (l & 15)]);
    }
    if (i < L * HD * HD) {
        int li = i >> 12, ii = i & 4095;
        int j = ii & 7, l = (ii >> 3) & 63, t = (ii >> 9) & 3, c = (ii >> 11) & 1;
        int k = c * 32 + ((l >> 4) * 8) + j;
        int col = t * 16 + (l & 15);
        float beta = logf(0.5f / (float)(li + 1) + 1.0f);
        float v = beta * Wlay[(size_t)li * HD * HD + k * HD + col] +
                  ((k == col) ? (1.f - beta) : 0.f);
        Wf2[i] = f2bf(v);
    }
    if (i < HD * HD) {
        int j = i & 7, l = (i >> 3) & 63, t = (i >> 9) & 3, c = (i >> 11) & 1;
        int k = c * 32 + ((l >> 4) * 8) + j;
        int col = t * 16 + (l & 15);
        Wfo[i] = (col < NC) ? f2bf(Wo[k * NC + col]) : (ushort)0;
    }
    if (i < HD) bo_pad[i] = (i < NC) ? bo[i] : 0.f;
}

// ---------------- fused: proj (MFMA) interleaved with edge histogram --------------
// Block role by blockIdx%k: r==0 -> proj tile q, else hist tile (2 edges/thread —
// R17 post-mortem: 4/thread cut occupancy and regressed; 2 is the measured best).

__global__ __launch_bounds__(256) void histproj_kernel(
        const int* __restrict__ dst, const float* __restrict__ w,
        uint* packed8, ushort* __restrict__ rank, int E, int n,
        const float* __restrict__ x, const ushort* __restrict__ Wf,
        const float* __restrict__ bias, ushort* __restrict__ h0,
        int npb, int k) {
    const int q = blockIdx.x / k;
    const int r = blockIdx.x - q * k;
    if (r != 0) {
        int hid = q * (k - 1) + (r - 1);
        int i1 = hid * 512 + threadIdx.x;
        int i2 = i1 + 256;
        if (i1 < E) {
            int d = dst[i1];
            int c = i1 & 7;
            uint add = (1u << 26) | (uint)(w[i1] * 2097152.0f);
            uint old = atomicAdd(&packed8[(size_t)c * n + d], add);
            rank[i1] = (ushort)(old >> 26);
        }
        if (i2 < E) {
            int d = dst[i2];
            int c = i2 & 7;
            uint add = (1u << 26) | (uint)(w[i2] * 2097152.0f);
            uint old = atomicAdd(&packed8[(size_t)c * n + d], add);
            rank[i2] = (ushort)(old >> 26);
        }
        return;
    }
    const int lane = threadIdx.x & 63;
    const int wave = threadIdx.x >> 6;
    const int row = lane & 15;
    const int g = lane >> 4;
    const int base = q * 64 + wave * 16;

    f32x4 acc[4];
#pragma unroll
    for (int t = 0; t < 4; ++t) acc[t] = (f32x4){0.f, 0.f, 0.f, 0.f};

    int nodeA = base + row;
    if (nodeA >= n) nodeA = n - 1;
    const float* xr = x + (size_t)nodeA * FIN + g * 8;

    for (int c = 0; c < 16; ++c) {
        bf16x8 afr;
        float4 v0 = *(const float4*)(xr + c * 32);
        float4 v1 = *(const float4*)(xr + c * 32 + 4);
        afr[0] = (short)f2bf(v0.x); afr[1] = (short)f2bf(v0.y);
        afr[2] = (short)f2bf(v0.z); afr[3] = (short)f2bf(v0.w);
        afr[4] = (short)f2bf(v1.x); afr[5] = (short)f2bf(v1.y);
        afr[6] = (short)f2bf(v1.z); afr[7] = (short)f2bf(v1.w);
#pragma unroll
        for (int t = 0; t < 4; ++t) {
            bf16x8 bfr = *(const bf16x8*)(Wf + ((size_t)(c * 4 + t) * 64 + lane) * 8);
            acc[t] = __builtin_amdgcn_mfma_f32_16x16x32_bf16(afr, bfr, acc[t], 0, 0, 0);
        }
    }

    float bj[4];
#pragma unroll
    for (int t = 0; t < 4; ++t) bj[t] = bias[t * 16 + row];
#pragma unroll
    for (int rr = 0; rr < 4; ++rr) {
        int node = base + g * 4 + rr;
        if (node < n) {
#pragma unroll
            for (int t = 0; t < 4; ++t) {
                float v = fmaxf(acc[t][rr] + bj[t], 0.f);
                h0[(size_t)node * HD + t * 16 + row] = f2bf(v);
            }
        }
    }
}

// fused: dinv + copy-bases (8 bytes in uint2) + per-block count scan
__global__ __launch_bounds__(256) void post_kernel(const uint* __restrict__ packed8,
        float* __restrict__ dinv, uint2* __restrict__ cbase,
        int* __restrict__ row_ptr, int* __restrict__ bsums, int n) {
    __shared__ int s[256];
    int t = threadIdx.x;
    int i = blockIdx.x * 256 + t;
    int cnt = 0;
    if (i < n) {
        int c[8];
        unsigned long long fx = 0;
#pragma unroll
        for (int k = 0; k < 8; ++k) {
            uint p = packed8[(size_t)k * n + i];
            c[k] = (int)(p >> 26);
            fx += (p & 0x3FFFFFFu);
        }
        float deg = (float)((double)fx * (1.0 / 2097152.0));
        dinv[i] = rsqrtf(deg);                     // deg >= 1 (self-loop)
        int b = 0; uint lo = 0, hi = 0;
#pragma unroll
        for (int k = 0; k < 4; ++k) { lo |= ((uint)b) << (8 * k); b += c[k]; }
#pragma unroll
        for (int k = 0; k < 4; ++k) { hi |= ((uint)b) << (8 * k); b += c[4 + k]; }
        cbase[i] = make_uint2(lo, hi);
        cnt = b;
    }
    s[t] = cnt; __syncthreads();
    for (int off = 1; off < 256; off <<= 1) {
        int u = (t >= off) ? s[t - off] : 0;
        __syncthreads();
        s[t] += u;
        __syncthreads();
    }
    if (i < n) row_ptr[i] = s[t] - cnt;
    if (t == 255) bsums[blockIdx.x] = s[255];
}

// fused top-scan + add: block b reduces bsums[0..b-1] itself (nb < 512)
__global__ __launch_bounds__(256) void scanadd_kernel(int* __restrict__ row_ptr,
        const int* __restrict__ bsums, int n, int E) {
    __shared__ int s[256];
    const int b = blockIdx.x;
    const int t = threadIdx.x;
    int v = (t < b) ? bsums[t] : 0;
    if (t + 256 < b) v += bsums[t + 256];
    s[t] = v; __syncthreads();
#pragma unroll
    for (int off = 128; off >= 1; off >>= 1) {
        if (t < off) s[t] += s[t + off];
        __syncthreads();
    }
    int prefix = s[0];
    int i = b * 256 + t;
    if (i < n) row_ptr[i] += prefix;
    if (i == 0) row_ptr[n] = E;
}

__global__ __launch_bounds__(256) void scatter_kernel(const int* __restrict__ src,
        const int* __restrict__ dst, const float* __restrict__ w,
        const float* __restrict__ dinv, const int* __restrict__ row_ptr,
        const uint2* __restrict__ cbase, const ushort* __restrict__ rank,
        EdgeT* __restrict__ ed, int E) {
    int i = blockIdx.x * 256 + threadIdx.x;
    if (i < E) {
        int s = src[i], d = dst[i];
        int c = i & 7;
        uint2 cb = cbase[d];
        int base = (int)(((c < 4) ? (cb.x >> (8 * c)) : (cb.y >> (8 * (c - 4)))) & 0xffu);
        int pos = row_ptr[d] + base + (int)rank[i];
        EdgeT e; e.s = s; e.v = dinv[s] * w[i] * dinv[d];
        ed[pos] = e;
    }
}

// ---------------- fused layer: gather(spmm) + MFMA GEMM(W') + relu ---------------
// Gather unroll 4 (R17 post-mortem: unroll 8 cost VGPR/occupancy and regressed).

__global__ __launch_bounds__(256) void layerm_kernel(const ushort* __restrict__ h_in,
        const ushort* __restrict__ h0, ushort* __restrict__ h_out,
        const ushort* __restrict__ Wf2, const float* __restrict__ dinv,
        const int* __restrict__ row_ptr, const EdgeT* __restrict__ ed, int n) {
    __shared__ ushort S[4][32 * 72];       // 18.4 KB
    const int lane = threadIdx.x & 63;
    const int wave = threadIdx.x >> 6;
    ushort* Sw = S[wave];
    const int wbase = (blockIdx.x * 4 + wave) * 32;
    const int gs = lane >> 3;              // node slot 0..7
    const int fl = (lane & 7) * 8;         // feature offset

#pragma unroll
    for (int p = 0; p < 4; ++p) {
        int node = wbase + p * 8 + gs;
        int nc = (node < n) ? node : n - 1;
        float di = dinv[nc];
        float sw = di * di;
        u16x8 us = *(const u16x8*)(h_in + (size_t)nc * HD + fl);
        float a[8], b[8];
#pragma unroll
        for (int j = 0; j < 8; ++j) { a[j] = sw * bf2f((ushort)us[j]); b[j] = 0.f; }

        int e = row_ptr[nc], end = row_ptr[nc + 1];
        for (; e + 4 <= end; e += 4) {
            EdgeT E0 = ed[e], E1 = ed[e + 1], E2 = ed[e + 2], E3 = ed[e + 3];
            u16x8 u0 = *(const u16x8*)(h_in + (size_t)E0.s * HD + fl);
            u16x8 u1 = *(const u16x8*)(h_in + (size_t)E1.s * HD + fl);
            u16x8 u2 = *(const u16x8*)(h_in + (size_t)E2.s * HD + fl);
            u16x8 u3 = *(const u16x8*)(h_in + (size_t)E3.s * HD + fl);
#pragma unroll
            for (int j = 0; j < 8; ++j) {
                a[j] = fmaf(E0.v, bf2f((ushort)u0[j]), a[j]);
                b[j] = fmaf(E1.v, bf2f((ushort)u1[j]), b[j]);
                a[j] = fmaf(E2.v, bf2f((ushort)u2[j]), a[j]);
                b[j] = fmaf(E3.v, bf2f((ushort)u3[j]), b[j]);
            }
        }
        for (; e < end; ++e) {
            EdgeT E0 = ed[e];
            u16x8 u0 = *(const u16x8*)(h_in + (size_t)E0.s * HD + fl);
#pragma unroll
            for (int j = 0; j < 8; ++j) a[j] = fmaf(E0.v, bf2f((ushort)u0[j]), a[j]);
        }

        u16x8 uh = *(const u16x8*)(h0 + (size_t)nc * HD + fl);
        u16x8 r;
#pragma unroll
        for (int j = 0; j < 8; ++j)
            r[j] = f2bf(fmaf(0.9f, a[j] + b[j], 0.1f * bf2f((ushort)uh[j])));
        *(u16x8*)(Sw + (p * 8 + gs) * 72 + fl) = r;
    }

    asm volatile("s_waitcnt lgkmcnt(0)" ::: "memory");
    __builtin_amdgcn_wave_barrier();
    __builtin_amdgcn_sched_barrier(0);

    // ---- MFMA: 32 nodes x 64 cols, W' includes residual ----
    const int row = lane & 15;
    const int g = lane >> 4;
    f32x4 acc[2][4];
#pragma unroll
    for (int m = 0; m < 2; ++m)
#pragma unroll
        for (int t = 0; t < 4; ++t) acc[m][t] = (f32x4){0.f, 0.f, 0.f, 0.f};

#pragma unroll
    for (int c = 0; c < 2; ++c) {
        bf16x8 afr[2];
#pragma unroll
        for (int m = 0; m < 2; ++m)
            afr[m] = *(const bf16x8*)(Sw + (m * 16 + row) * 72 + c * 32 + g * 8);
#pragma unroll
        for (int t = 0; t < 4; ++t) {
            bf16x8 bfr = *(const bf16x8*)(Wf2 + ((size_t)(c * 4 + t) * 64 + lane) * 8);
            acc[0][t] = __builtin_amdgcn_mfma_f32_16x16x32_bf16(afr[0], bfr, acc[0][t], 0, 0, 0);
            acc[1][t] = __builtin_amdgcn_mfma_f32_16x16x32_bf16(afr[1], bfr, acc[1][t], 0, 0, 0);
        }
    }

#pragma unroll
    for (int m = 0; m < 2; ++m)
#pragma unroll
        for (int r = 0; r < 4; ++r) {
            int node = wbase + m * 16 + g * 4 + r;
            if (node < n) {
#pragma unroll
                for (int t = 0; t < 4; ++t) {
                    float v = fmaxf(acc[m][t][r], 0.f);
                    h_out[(size_t)node * HD + t * 16 + row] = f2bf(v);
                }
            }
        }
}

// ---------------- output (MFMA) + log_softmax: out = lsm(h @ W_out + b) ----------

__global__ __launch_bounds__(256) void outm_kernel(const ushort* __restrict__ A,
        const ushort* __restrict__ Wfo, const float* __restrict__ bo_pad,
        float* __restrict__ outp, int n) {
    const int lane = threadIdx.x & 63;
    const int wave = threadIdx.x >> 6;
    const int row = lane & 15;
    const int g = lane >> 4;
    const int base = blockIdx.x * 128 + wave * 32;

    f32x4 acc[2][4];
#pragma unroll
    for (int m = 0; m < 2; ++m)
#pragma unroll
        for (int t = 0; t < 4; ++t) acc[m][t] = (f32x4){0.f, 0.f, 0.f, 0.f};

#pragma unroll
    for (int c = 0; c < 2; ++c) {
        bf16x8 afr[2];
#pragma unroll
        for (int m = 0; m < 2; ++m) {
            int node = base + m * 16 + row;
            if (node >= n) node = n - 1;
            afr[m] = *(const bf16x8*)(A + (size_t)node * HD + c * 32 + g * 8);
        }
#pragma unroll
        for (int t = 0; t < 4; ++t) {
            bf16x8 bfr = *(const bf16x8*)(Wfo + ((size_t)(c * 4 + t) * 64 + lane) * 8);
            acc[0][t] = __builtin_amdgcn_mfma_f32_16x16x32_bf16(afr[0], bfr, acc[0][t], 0, 0, 0);
            acc[1][t] = __builtin_amdgcn_mfma_f32_16x16x32_bf16(afr[1], bfr, acc[1][t], 0, 0, 0);
        }
    }

    float bj[4];
#pragma unroll
    for (int t = 0; t < 4; ++t) bj[t] = bo_pad[t * 16 + row];
    const bool v2 = (row < 8);             // col = 32+row < 40
#pragma unroll
    for (int m = 0; m < 2; ++m)
#pragma unroll
        for (int r = 0; r < 4; ++r) {
            float lo[3];
            lo[0] = acc[m][0][r] + bj[0];
            lo[1] = acc[m][1][r] + bj[1];
            lo[2] = acc[m][2][r] + bj[2];
            float mx = fmaxf(lo[0], lo[1]);
            if (v2) mx = fmaxf(mx, lo[2]);
#pragma unroll
            for (int off = 1; off < 16; off <<= 1)
                mx = fmaxf(mx, __shfl_xor(mx, off, 64));
            float s = __expf(lo[0] - mx) + __expf(lo[1] - mx);
            if (v2) s += __expf(lo[2] - mx);
#pragma unroll
            for (int off = 1; off < 16; off <<= 1)
                s += __shfl_xor(s, off, 64);
            float lse = __logf(s);
            int node = base + m * 16 + g * 4 + r;
            if (node < n) {
                outp[(size_t)node * NC + row] = lo[0] - mx - lse;
                outp[(size_t)node * NC + 16 + row] = lo[1] - mx - lse;
                if (v2) outp[(size_t)node * NC + 32 + row] = lo[2] - mx - lse;
            }
        }
}

// ---------------- launch ----------------

extern "C" void kernel_launch(void* const* d_in, const int* in_sizes, int n_in,
                              void* d_out, int out_size, void* d_ws, size_t ws_size,
                              hipStream_t stream) {
    const float* x        = (const float*)d_in[0];
    const int*   eidx     = (const int*)d_in[1];
    const float* ew       = (const float*)d_in[2];
    const float* W_in     = (const float*)d_in[3];
    const float* b_in     = (const float*)d_in[4];
    const float* W_layers = (const float*)d_in[5];
    const float* W_out    = (const float*)d_in[6];
    const float* b_out    = (const float*)d_in[7];
    float* out = (float*)d_out;

    const int N = in_sizes[0] / FIN;
    const int E = in_sizes[2];
    const int L = in_sizes[5] / (HD * HD);
    const int* src = eidx;
    const int* dst = eidx + E;

    size_t off = 0;
    auto carve = [&](size_t bytes) {
        void* p = (char*)d_ws + off;
        off += (bytes + 255) & ~(size_t)255;
        return p;
    };
    uint*   packed8 = (uint*) carve((size_t)N * 8 * 4);
    float*  dinv    = (float*)carve((size_t)N * 4);
    uint2*  cbase   = (uint2*)carve((size_t)N * 8);
    int*    row_ptr = (int*)  carve((size_t)(N + 1) * 4);
    int*    bsums   = (int*)  carve(512 * 4);
    float*  bo_pad  = (float*)carve((size_t)HD * 4);
    ushort* Wf      = (ushort*)carve((size_t)FIN * HD * 2);
    ushort* Wf2     = (ushort*)carve((size_t)L * HD * HD * 2);
    ushort* Wfo     = (ushort*)carve((size_t)HD * HD * 2);
    ushort* rank    = (ushort*)carve((size_t)E * 2);
    EdgeT*  ed      = (EdgeT*)carve((size_t)E * 8);
    ushort* h0      = (ushort*)carve((size_t)N * HD * 2);
    ushort* hA      = (ushort*)carve((size_t)N * HD * 2);
    ushort* hB      = (ushort*)carve((size_t)N * HD * 2);
    (void)ws_size;

    const int NB = (N + 255) / 256;
    const int EB = (E + 255) / 256;
    const int NPB = (N + 63) / 64;           // proj blocks
    const int HB  = (E + 511) / 512;         // hist blocks (2 edges/thread)
    const int K   = (NPB + HB + NPB - 1) / NPB;
    const int GRID = NPB * K;

    prep_kernel<<<(8 * N + 255) / 256, 256, 0, stream>>>(packed8, N, W_in, Wf,
                                                         W_layers, Wf2, L,
                                                         W_out, b_out, Wfo, bo_pad);
    histproj_kernel<<<GRID, 256, 0, stream>>>(dst, ew, packed8, rank, E, N,
                                              x, Wf, b_in, h0, NPB, K);
    post_kernel<<<NB, 256, 0, stream>>>(packed8, dinv, cbase, row_ptr, bsums, N);
    scanadd_kernel<<<NB, 256, 0, stream>>>(row_ptr, bsums, N, E);
    scatter_kernel<<<EB, 256, 0, stream>>>(src, dst, ew, dinv, row_ptr, cbase, rank, ed, E);

    const int LB = (N + 127) / 128;          // 4 waves x 32 nodes
    const ushort* cur = h0;
    ushort* bufs[2] = { hA, hB };
    for (int i = 0; i < L; ++i) {
        ushort* nxt = bufs[i & 1];
        layerm_kernel<<<LB, 256, 0, stream>>>(cur, h0, nxt, Wf2 + (size_t)i * HD * HD,
                                              dinv, row_ptr, ed, N);
        cur = nxt;
    }

    outm_kernel<<<LB, 256, 0, stream>>>(cur, Wfo, bo_pad, out, N);
}